// Round 1
// baseline (16853.725 us; speedup 1.0000x reference)
//
#include <hip/hip_runtime.h>
#include <math.h>

// ---- problem constants
#define BATCH  256
#define CODE   64
#define HID    256
#define TSTEPS 640     // 512 encoder + 128 decoder steps
#define NB     16      // batch elements per group
#define GWG    16      // workgroups per group
#define NGRP   16      // groups (NGRP*NB = BATCH)

// ---- workspace layout (float offsets)
#define OFF_WT0IH 0                           // [64][1024]
#define OFF_WT0HH (OFF_WT0IH + 64*1024)       // [256][1024]
#define OFF_WT1IH (OFF_WT0HH + 256*1024)      // [256][1024]
#define OFF_WT1HH (OFF_WT1IH + 256*1024)      // [256][1024]
#define OFF_B0    (OFF_WT1HH + 256*1024)      // [1024]
#define OFF_B1    (OFF_B0 + 1024)             // [1024]
#define OFF_FCWT  (OFF_B1 + 1024)             // [256][64]
#define OFF_H0    (OFF_FCWT + 64*256)         // [2][NGRP][256][16]
#define OFF_H1    (OFF_H0 + 2*NGRP*HID*NB)    // [2][NGRP][256][16]
#define OFF_CNT   (OFF_H1 + 2*NGRP*HID*NB)    // NGRP counters, 128B apart
#define WS_FLOATS (OFF_CNT + NGRP*32)

__device__ __forceinline__ float ld_byp(const float* p) {
  return __hip_atomic_load(p, __ATOMIC_RELAXED, __HIP_MEMORY_SCOPE_AGENT);
}
__device__ __forceinline__ void st_byp(float* p, float v) {
  __hip_atomic_store(p, v, __ATOMIC_RELAXED, __HIP_MEMORY_SCOPE_AGENT);
}
__device__ __forceinline__ float sigm(float v) { return 1.0f / (1.0f + expf(-v)); }

// ---- one-time weight transpose / bias fuse into ws
__global__ void setup_kernel(const float* __restrict__ Wih0, const float* __restrict__ Whh0,
                             const float* __restrict__ bih0, const float* __restrict__ bhh0,
                             const float* __restrict__ Wih1, const float* __restrict__ Whh1,
                             const float* __restrict__ bih1, const float* __restrict__ bhh1,
                             const float* __restrict__ fcW, float* __restrict__ ws) {
  int i = blockIdx.x * blockDim.x + threadIdx.x;
  if (i < 65536)  { ws[OFF_WT0IH + i] = Wih0[(i & 1023) * 64  + (i >> 10)]; return; }
  i -= 65536;
  if (i < 262144) { ws[OFF_WT0HH + i] = Whh0[(i & 1023) * 256 + (i >> 10)]; return; }
  i -= 262144;
  if (i < 262144) { ws[OFF_WT1IH + i] = Wih1[(i & 1023) * 256 + (i >> 10)]; return; }
  i -= 262144;
  if (i < 262144) { ws[OFF_WT1HH + i] = Whh1[(i & 1023) * 256 + (i >> 10)]; return; }
  i -= 262144;
  if (i < 1024)   { ws[OFF_B0 + i] = bih0[i] + bhh0[i]; return; }
  i -= 1024;
  if (i < 1024)   { ws[OFF_B1 + i] = bih1[i] + bhh1[i]; return; }
  i -= 1024;
  if (i < 16384)  { ws[OFF_FCWT + i] = fcW[(i & 63) * 256 + (i >> 6)]; return; }
}

// ---- persistent pipelined LSTM kernel
// grid = 256 WGs x 512 threads. 16 groups x 16 WGs. Each WG: 16 units of all 4
// gates, both layers. Threads 0..255 = layer0 (step tick), 256..511 = layer1
// (step tick-1). One per-group global barrier per tick.
__global__ __launch_bounds__(512) void lstm_persistent(
    const float* __restrict__ x, const float* __restrict__ targets,
    const float* __restrict__ fcb, float* __restrict__ ws, float* __restrict__ out) {
  __shared__ float xT[CODE * NB];      // [k][b]
  __shared__ float h0T[HID * NB];      // [k][b]  h0(tick-1)
  __shared__ float h1T[HID * NB];      // [k][b]  h1(tick-2)
  __shared__ float gbuf0[64 * NB];     // [gate-lane][b]
  __shared__ float gbuf1[64 * NB];
  __shared__ float c0s[NB * NB];       // [unit][b]
  __shared__ float c1s[NB * NB];

  const int t = threadIdx.x;
  const int blk = blockIdx.x;
  // XCD-locality heuristic grouping (correctness does not depend on it)
  const int xcd = blk & 7;
  const int slot = blk >> 3;
  const int grp = xcd * 2 + (slot >> 4);   // 0..15
  const int wg  = slot & 15;               // 0..15

  float* H0base = ws + OFF_H0;
  float* H1base = ws + OFF_H1;
  unsigned* cnt = (unsigned*)(ws + OFF_CNT) + grp * 32;

  const int half = t >> 8;      // 0: layer0, 1: layer1
  const int tl = t & 255;
  const int l  = tl & 63;       // gate lane: type = l>>4, unit-in-slice = l&15
  const int bq = tl >> 6;       // batch quad 0..3
  const int gj = ((l >> 4) << 8) + (wg << 4) + (l & 15);  // global gate row 0..1023
  const int uu = tl >> 4;       // update role: unit 0..15
  const int ub = tl & 15;       // update role: batch 0..15
  const int gu = (wg << 4) + uu;

  const float* WT0ih = ws + OFF_WT0IH;
  const float* WT0hh = ws + OFF_WT0HH;
  const float* WT1ih = ws + OFF_WT1IH;
  const float* WT1hh = ws + OFF_WT1HH;
  const float* fcWT  = ws + OFF_FCWT;
  const float bias = (half == 0) ? ws[OFF_B0 + gj] : ws[OFF_B1 + gj];

  if (t < 256) { c0s[t] = 0.0f; c1s[t] = 0.0f; }
  __syncthreads();

  for (int tick = 0; tick <= TSTEPS + 1; ++tick) {
    const int s0 = tick;         // layer0 step
    const int s1 = tick - 1;     // layer1 step
    const int rp = (tick + 1) & 1;
    const int wp = tick & 1;

    // ---- stage h0(tick-1), h1(tick-2), x(tick) into LDS
    {
      const float* src0 = H0base + (rp * NGRP + grp) * (HID * NB);
      const float* src1 = H1base + (rp * NGRP + grp) * (HID * NB);
#pragma unroll
      for (int i = 0; i < 8; ++i) {
        int idx = t + 512 * i;
        h0T[idx] = ld_byp(src0 + idx);
        h1T[idx] = ld_byp(src1 + idx);
      }
      if (s0 < TSTEPS) {
#pragma unroll
        for (int i = 0; i < 2; ++i) {
          int e = t + 512 * i;           // 0..1023
          int b = e >> 6, c = e & 63;
          int bg = grp * NB + b;
          float v;
          if (s0 < 512)       v = x[bg * 32768 + s0 * 64 + c];
          else if (s0 == 512) v = x[bg * 32768 + 511 * 64 + c];
          else                v = targets[bg * 8192 + (s0 - 513) * 64 + c];
          xT[c * NB + b] = v;
        }
      }
    }
    __syncthreads();

    // ---- gate dot products
    if (half == 0) {
      if (s0 < TSTEPS) {
        float a0 = bias, a1 = bias, a2 = bias, a3 = bias;
        const float* wp0 = WT0ih + gj;
#pragma unroll 8
        for (int k = 0; k < CODE; ++k) {
          float w = wp0[k << 10];
          float4 v = *(const float4*)(xT + (k << 4) + (bq << 2));
          a0 = fmaf(w, v.x, a0); a1 = fmaf(w, v.y, a1);
          a2 = fmaf(w, v.z, a2); a3 = fmaf(w, v.w, a3);
        }
        const float* wp1 = WT0hh + gj;
#pragma unroll 8
        for (int k = 0; k < HID; ++k) {
          float w = wp1[k << 10];
          float4 v = *(const float4*)(h0T + (k << 4) + (bq << 2));
          a0 = fmaf(w, v.x, a0); a1 = fmaf(w, v.y, a1);
          a2 = fmaf(w, v.z, a2); a3 = fmaf(w, v.w, a3);
        }
        *(float4*)(gbuf0 + (l << 4) + (bq << 2)) = float4{a0, a1, a2, a3};
      }
    } else {
      if (s1 >= 0 && s1 < TSTEPS) {
        float a0 = bias, a1 = bias, a2 = bias, a3 = bias;
        const float* wp0 = WT1ih + gj;
#pragma unroll 8
        for (int k = 0; k < HID; ++k) {   // input = h0(tick-1)
          float w = wp0[k << 10];
          float4 v = *(const float4*)(h0T + (k << 4) + (bq << 2));
          a0 = fmaf(w, v.x, a0); a1 = fmaf(w, v.y, a1);
          a2 = fmaf(w, v.z, a2); a3 = fmaf(w, v.w, a3);
        }
        const float* wp1 = WT1hh + gj;
#pragma unroll 8
        for (int k = 0; k < HID; ++k) {   // recurrent = h1(tick-2)
          float w = wp1[k << 10];
          float4 v = *(const float4*)(h1T + (k << 4) + (bq << 2));
          a0 = fmaf(w, v.x, a0); a1 = fmaf(w, v.y, a1);
          a2 = fmaf(w, v.z, a2); a3 = fmaf(w, v.w, a3);
        }
        *(float4*)(gbuf1 + (l << 4) + (bq << 2)) = float4{a0, a1, a2, a3};
      }
    }
    __syncthreads();

    // ---- c/h update (i,f,g,o -> c,h), write h slice to global exchange buf
    if (half == 0) {
      if (s0 < TSTEPS) {
        float iv = gbuf0[(uu << 4) + ub];
        float fv = gbuf0[((16 + uu) << 4) + ub];
        float gv = gbuf0[((32 + uu) << 4) + ub];
        float ov = gbuf0[((48 + uu) << 4) + ub];
        float cc = sigm(fv) * c0s[(uu << 4) + ub] + sigm(iv) * tanhf(gv);
        c0s[(uu << 4) + ub] = cc;
        float hh = sigm(ov) * tanhf(cc);
        st_byp(H0base + (wp * NGRP + grp) * (HID * NB) + (gu << 4) + ub, hh);
      }
    } else {
      if (s1 >= 0 && s1 < TSTEPS) {
        float iv = gbuf1[(uu << 4) + ub];
        float fv = gbuf1[((16 + uu) << 4) + ub];
        float gv = gbuf1[((32 + uu) << 4) + ub];
        float ov = gbuf1[((48 + uu) << 4) + ub];
        float cc = sigm(fv) * c1s[(uu << 4) + ub] + sigm(iv) * tanhf(gv);
        c1s[(uu << 4) + ub] = cc;
        float hh = sigm(ov) * tanhf(cc);
        st_byp(H1base + (wp * NGRP + grp) * (HID * NB) + (gu << 4) + ub, hh);
      }
    }

    // ---- decoder output projection: h1T holds h1(tick-2); dec step = tick-514
    if (tick >= 514) {
      int d = tick - 514;
      int c = t & 63, bb = t >> 6;   // bb 0..7, handles batches bb and bb+8
      float o0 = fcb[c], o1 = fcb[c];
#pragma unroll 8
      for (int k = 0; k < HID; ++k) {
        float w = fcWT[(k << 6) + c];
        o0 = fmaf(w, h1T[(k << 4) + bb], o0);
        o1 = fmaf(w, h1T[(k << 4) + bb + 8], o1);
      }
      out[(grp * NB + bb) * 8192 + d * 64 + c] = o0;
      out[(grp * NB + bb + 8) * 8192 + d * 64 + c] = o1;
    }

    // ---- per-group barrier (monotonic counter)
    if (tick < TSTEPS + 1) {
      __syncthreads();   // all h stores drained (vmcnt(0) before s_barrier)
      if (t == 0) {
        __hip_atomic_fetch_add(cnt, 1u, __ATOMIC_RELEASE, __HIP_MEMORY_SCOPE_AGENT);
        unsigned target = (unsigned)(GWG * (tick + 1));
        while (__hip_atomic_load(cnt, __ATOMIC_ACQUIRE, __HIP_MEMORY_SCOPE_AGENT) < target)
          __builtin_amdgcn_s_sleep(1);
      }
      __syncthreads();
    }
  }
}

extern "C" void kernel_launch(void* const* d_in, const int* in_sizes, int n_in,
                              void* d_out, int out_size, void* d_ws, size_t ws_size,
                              hipStream_t stream) {
  const float* x       = (const float*)d_in[0];
  const float* targets = (const float*)d_in[1];
  const float* Wih0    = (const float*)d_in[2];
  const float* Whh0    = (const float*)d_in[3];
  const float* bih0    = (const float*)d_in[4];
  const float* bhh0    = (const float*)d_in[5];
  const float* Wih1    = (const float*)d_in[6];
  const float* Whh1    = (const float*)d_in[7];
  const float* bih1    = (const float*)d_in[8];
  const float* bhh1    = (const float*)d_in[9];
  const float* fcW     = (const float*)d_in[10];
  const float* fcb     = (const float*)d_in[11];
  float* ws = (float*)d_ws;
  float* o  = (float*)d_out;

  // zero h-exchange buffers + barrier counters (every call: deterministic)
  hipMemsetAsync((char*)d_ws + (size_t)OFF_H0 * 4, 0,
                 (size_t)(WS_FLOATS - OFF_H0) * 4, stream);
  setup_kernel<<<3400, 256, 0, stream>>>(Wih0, Whh0, bih0, bhh0,
                                         Wih1, Whh1, bih1, bhh1, fcW, ws);
  lstm_persistent<<<256, 512, 0, stream>>>(x, targets, fcb, ws, o);
}

// Round 2
// 4679.255 us; speedup vs baseline: 3.6018x; 3.6018x over previous
//
#include <hip/hip_runtime.h>
#include <math.h>

#define BATCH  256
#define CODE   64
#define HID    256
#define TSTEPS 640     // 512 encoder + 128 decoder steps
#define NB     16
#define GWG    16
#define NGRP   16

// ---- workspace layout (float offsets)
#define OFF_A0   0          // [64rt][10f][2pl][64lane][16B bf16]  = 327680 floats
#define OFF_A1   327680     // [64rt][16f][2pl][64lane][16B bf16]  = 524288 floats
#define OFF_BP0  851968     // [1024] permuted fused bias layer0
#define OFF_BP1  852992     // [1024]
#define OFF_H0EX 854016     // [2buf][16grp][16batch][256unit] bf16 = 65536 floats
#define OFF_H1EX 919552     // same
#define OFF_CNT  985088     // 16 groups * 32 uints
#define WS_FLOATS (OFF_CNT + 512)

typedef __attribute__((ext_vector_type(8))) short  short8;
typedef __attribute__((ext_vector_type(4))) float  f32x4;
typedef __attribute__((ext_vector_type(8))) __bf16 bf16x8;
typedef unsigned long long u64;

__device__ __forceinline__ f32x4 mfma16(short8 a, short8 b, f32x4 c) {
  return __builtin_amdgcn_mfma_f32_16x16x32_bf16(
      __builtin_bit_cast(bf16x8, a), __builtin_bit_cast(bf16x8, b), c, 0, 0, 0);
}
__device__ __forceinline__ unsigned short f2bf(float f) {
  union { float f; unsigned u; } v{f};
  unsigned r = v.u + 0x7fffu + ((v.u >> 16) & 1u);   // RNE
  return (unsigned short)(r >> 16);
}
__device__ __forceinline__ float bf2f(unsigned short b) {
  union { unsigned u; float f; } v{(unsigned)b << 16};
  return v.f;
}
__device__ __forceinline__ u64 ld8(const u64* p) {
  return __hip_atomic_load(p, __ATOMIC_RELAXED, __HIP_MEMORY_SCOPE_AGENT);
}
__device__ __forceinline__ void st8(u64* p, u64 v) {
  __hip_atomic_store(p, v, __ATOMIC_RELAXED, __HIP_MEMORY_SCOPE_AGENT);
}
__device__ __forceinline__ float sigm(float v) { return 1.0f / (1.0f + expf(-v)); }

// ---- one-time weight swizzle into MFMA fragment order, hi/lo bf16 split.
// Permuted gate row p (0..1023): orig_row(p) = (p&3)*256 + (p>>2)
//   -> row-tile rt covers units 4rt..4rt+3; lane-group g owns unit 4rt+g,
//      C regs r=0..3 are gates i,f,g,o of that unit.
// A-frag element (lane l, j): row = l&15, k = f*32 + (l>>4)*8 + j.
__global__ void setup_kernel(const float* __restrict__ Wih0, const float* __restrict__ Whh0,
                             const float* __restrict__ bih0, const float* __restrict__ bhh0,
                             const float* __restrict__ Wih1, const float* __restrict__ Whh1,
                             const float* __restrict__ bih1, const float* __restrict__ bhh1,
                             float* __restrict__ ws) {
  int i = blockIdx.x * 256 + threadIdx.x;
  unsigned short* u = (unsigned short*)ws;
  if (i < 327680) {        // layer0: K = 320 (64 x | 256 h0)
    int rt = i / 5120, r = i % 5120;
    int f = r >> 9, l = (r >> 3) & 63, j = r & 7;
    int p = rt * 16 + (l & 15);
    int orig = (p & 3) * 256 + (p >> 2);
    int k = f * 32 + ((l >> 4) << 3) + j;
    float w = (k < 64) ? Wih0[orig * 64 + k] : Whh0[orig * 256 + k - 64];
    unsigned short hi = f2bf(w);
    unsigned short lo = f2bf(w - bf2f(hi));
    int base = OFF_A0 * 2 + (((rt * 10 + f) * 2) * 64 + l) * 8 + j;
    u[base] = hi; u[base + 512] = lo;
    return;
  }
  i -= 327680;
  if (i < 524288) {        // layer1: K = 512 (256 h0 | 256 h1)
    int rt = i >> 13, r = i & 8191;
    int f = r >> 9, l = (r >> 3) & 63, j = r & 7;
    int p = rt * 16 + (l & 15);
    int orig = (p & 3) * 256 + (p >> 2);
    int k = f * 32 + ((l >> 4) << 3) + j;
    float w = (k < 256) ? Wih1[orig * 256 + k] : Whh1[orig * 256 + k - 256];
    unsigned short hi = f2bf(w);
    unsigned short lo = f2bf(w - bf2f(hi));
    int base = OFF_A1 * 2 + (((rt * 16 + f) * 2) * 64 + l) * 8 + j;
    u[base] = hi; u[base + 512] = lo;
    return;
  }
  i -= 524288;
  if (i < 2048) {          // permuted fused biases
    int layer = i >> 10, p = i & 1023;
    int orig = (p & 3) * 256 + (p >> 2);
    ws[OFF_BP0 + i] = layer ? (bih1[orig] + bhh1[orig]) : (bih0[orig] + bhh0[orig]);
  }
}

// ---- persistent MFMA LSTM. 256 WGs x 512 thr. 16 groups x 16 WGs.
// waves 0-3: layer0 row-tiles wg*4+w (step tick); waves 4-7: layer1 (tick-1).
// Wave 0 also does the fp32 FC projection during decoder ticks.
__global__ __launch_bounds__(512, 2) void lstm_mfma(
    const float* __restrict__ x, const float* __restrict__ targets,
    const float* __restrict__ fcW, const float* __restrict__ fcb,
    float* __restrict__ ws, float* __restrict__ out) {
  // B-frag regions: [0..1]=x (K 0..63), [2..9]=h0 (K 0..255), [10..17]=h1
  __shared__ __align__(16) short Bfrag[18][64][8];
  __shared__ float hstage[2][16][16];   // [layer][unit_local][batch]
  __shared__ float fcw_s[64 * 257];     // fcW[c][k] padded (bank-spread)

  const int t = threadIdx.x;
  const int blk = blockIdx.x;
  const int xcd = blk & 7, slot = blk >> 3;
  const int grp = xcd * 2 + (slot >> 4);   // 0..15
  const int wg  = slot & 15;               // 0..15

  const int w = t >> 6, l = t & 63, wl = w & 3;
  const bool isL0 = (w < 4);
  const int rt = wg * 4 + wl;

  unsigned short* h0ex = (unsigned short*)(ws + OFF_H0EX);
  unsigned short* h1ex = (unsigned short*)(ws + OFF_H1EX);
  unsigned* cnt = (unsigned*)(ws + OFF_CNT) + grp * 32;

  for (int idx = t; idx < 64 * 256; idx += 512)
    fcw_s[(idx >> 8) * 257 + (idx & 255)] = fcW[idx];

  // ---- register-resident A fragments (persist across all 641 steps)
  short8 Ah[16], Al[16];
  if (isL0) {
    const float* Ab = ws + OFF_A0 + rt * 5120;
#pragma unroll
    for (int f = 0; f < 10; ++f) {
      Ah[f] = *(const short8*)(Ab + ((f * 2 + 0) * 64 + l) * 4);
      Al[f] = *(const short8*)(Ab + ((f * 2 + 1) * 64 + l) * 4);
    }
  } else {
    const float* Ab = ws + OFF_A1 + rt * 8192;
#pragma unroll
    for (int f = 0; f < 16; ++f) {
      Ah[f] = *(const short8*)(Ab + ((f * 2 + 0) * 64 + l) * 4);
      Al[f] = *(const short8*)(Ab + ((f * 2 + 1) * 64 + l) * 4);
    }
  }
  const f32x4 bias = *(const f32x4*)(ws + (isL0 ? OFF_BP0 : OFF_BP1) + rt * 16 + ((l >> 4) << 2));
  const float fcb_r = fcb[4 * wg + (l & 3)];
  float cst = 0.0f;                    // cell state: one unit x one batch per lane

  for (int tick = 0; tick <= TSTEPS + 1; ++tick) {
    const int s0 = tick, s1 = tick - 1;
    const int rp = (tick + 1) & 1, wp = tick & 1;

    // ---- STAGE: build bf16 B-fragments in LDS (lane l -> slot l, conflict-free)
    {
      const int col = l & 15;
      const int k0 = (w << 5) + ((l >> 4) << 3);
      const unsigned short* s0p = h0ex + ((((rp * 16 + grp) * 16 + col) << 8) + k0);
      const unsigned short* s1p = h1ex + ((((rp * 16 + grp) * 16 + col) << 8) + k0);
      union { u64 q[2]; short8 v; } u0, u1;
      u0.q[0] = ld8((const u64*)s0p); u0.q[1] = ld8((const u64*)(s0p + 4));
      u1.q[0] = ld8((const u64*)s1p); u1.q[1] = ld8((const u64*)(s1p + 4));
      *(short8*)Bfrag[2 + w][l]  = u0.v;
      *(short8*)Bfrag[10 + w][l] = u1.v;
      if (w < 2 && s0 < TSTEPS) {      // x / teacher-forced decoder input
        int k = (w << 5) + ((l >> 4) << 3);
        const float* src;
        if (s0 <= 512) {
          int s = (s0 < 512) ? s0 : 511;
          src = x + ((size_t)(grp * 16 + col) * 512 + s) * 64 + k;
        } else {
          src = targets + ((size_t)(grp * 16 + col) * 128 + (s0 - 513)) * 64 + k;
        }
        short8 v;
#pragma unroll
        for (int j = 0; j < 8; ++j) v[j] = (short)f2bf(src[j]);
        *(short8*)Bfrag[w][l] = v;
      }
    }
    __syncthreads();

    // ---- COMPUTE: gate MFMA (hi/lo planes) + lane-local LSTM pointwise
    {
      const bool act = isL0 ? (s0 < TSTEPS) : (s1 >= 0 && s1 < TSTEPS);
      if (act) {
        f32x4 accH = {0.f, 0.f, 0.f, 0.f}, accL = {0.f, 0.f, 0.f, 0.f};
        if (isL0) {
#pragma unroll
          for (int f = 0; f < 10; ++f) {
            short8 b = *(const short8*)Bfrag[f][l];
            accH = mfma16(Ah[f], b, accH);
            accL = mfma16(Al[f], b, accL);
          }
        } else {
#pragma unroll
          for (int f = 0; f < 16; ++f) {
            short8 b = *(const short8*)Bfrag[2 + f][l];
            accH = mfma16(Ah[f], b, accH);
            accL = mfma16(Al[f], b, accL);
          }
        }
        float gi = accH.x + accL.x + bias.x;
        float gf = accH.y + accL.y + bias.y;
        float gg = accH.z + accL.z + bias.z;
        float go = accH.w + accL.w + bias.w;
        cst = sigm(gf) * cst + sigm(gi) * tanhf(gg);
        float hh = sigm(go) * tanhf(cst);
        hstage[isL0 ? 0 : 1][4 * wl + (l >> 4)][l & 15] = hh;
      }
      // FC projection (fp32) from this tick's staged h1 = h1(tick-2)
      if (w == 0 && tick >= 514) {
        int d = tick - 514;
        int code = 4 * wg + (l & 3), b = l >> 2;
        float acc = fcb_r;
#pragma unroll 4
        for (int k8 = 0; k8 < 32; ++k8) {
          short8 hv = *(const short8*)Bfrag[10 + (k8 >> 2)][(k8 & 3) * 16 + b];
#pragma unroll
          for (int j = 0; j < 8; ++j)
            acc = fmaf(fcw_s[code * 257 + k8 * 8 + j], bf2f((unsigned short)hv[j]), acc);
        }
        out[(size_t)(grp * 16 + b) * 8192 + d * 64 + code] = acc;
      }
    }
    __syncthreads();

    // ---- EXPORT: hstage -> global exchange (bf16x4 packed, 8B atomic stores)
    if (t < 128) {
      int layer = t >> 6, b = t & 15, uq = (t >> 4) & 3;
      bool valid = layer ? (s1 >= 0 && s1 < TSTEPS) : (s0 < TSTEPS);
      if (valid) {
        u64 q;
        unsigned short* qq = (unsigned short*)&q;
        int ul = 4 * uq;
        qq[0] = f2bf(hstage[layer][ul + 0][b]);
        qq[1] = f2bf(hstage[layer][ul + 1][b]);
        qq[2] = f2bf(hstage[layer][ul + 2][b]);
        qq[3] = f2bf(hstage[layer][ul + 3][b]);
        unsigned short* dst = (layer ? h1ex : h0ex) +
            ((((wp * 16 + grp) * 16 + b) << 8) + (wg << 4) + (uq << 2));
        st8((u64*)dst, q);
      }
    }

    // ---- per-group global barrier (monotonic counter)
    if (tick < TSTEPS + 1) {
      __syncthreads();
      if (t == 0) {
        __hip_atomic_fetch_add(cnt, 1u, __ATOMIC_RELEASE, __HIP_MEMORY_SCOPE_AGENT);
        unsigned target = (unsigned)(GWG * (tick + 1));
        while (__hip_atomic_load(cnt, __ATOMIC_ACQUIRE, __HIP_MEMORY_SCOPE_AGENT) < target)
          __builtin_amdgcn_s_sleep(2);
      }
      __syncthreads();
    }
  }
}

extern "C" void kernel_launch(void* const* d_in, const int* in_sizes, int n_in,
                              void* d_out, int out_size, void* d_ws, size_t ws_size,
                              hipStream_t stream) {
  const float* x       = (const float*)d_in[0];
  const float* targets = (const float*)d_in[1];
  const float* Wih0    = (const float*)d_in[2];
  const float* Whh0    = (const float*)d_in[3];
  const float* bih0    = (const float*)d_in[4];
  const float* bhh0    = (const float*)d_in[5];
  const float* Wih1    = (const float*)d_in[6];
  const float* Whh1    = (const float*)d_in[7];
  const float* bih1    = (const float*)d_in[8];
  const float* bhh1    = (const float*)d_in[9];
  const float* fcW     = (const float*)d_in[10];
  const float* fcb     = (const float*)d_in[11];
  float* ws = (float*)d_ws;
  float* o  = (float*)d_out;

  // zero h-exchange buffers + barrier counters every call (deterministic)
  hipMemsetAsync((char*)d_ws + (size_t)OFF_H0EX * 4, 0,
                 (size_t)(WS_FLOATS - OFF_H0EX) * 4, stream);
  setup_kernel<<<3336, 256, 0, stream>>>(Wih0, Whh0, bih0, bhh0,
                                         Wih1, Whh1, bih1, bhh1, ws);
  lstm_mfma<<<256, 512, 0, stream>>>(x, targets, fcW, fcb, ws, o);
}